// Round 1
// baseline (51.286 us; speedup 1.0000x reference)
//
#include <hip/hip_runtime.h>
#include <hip/hip_bf16.h>

#define ALPHA 0.2f
#define NEGINF -9000000000000000.0f

typedef __attribute__((ext_vector_type(8))) short short8;
typedef __attribute__((ext_vector_type(4))) float f32x4;
typedef __attribute__((ext_vector_type(4))) int i32x4;
typedef __attribute__((ext_vector_type(4))) unsigned short u16x4;

static constexpr int NB = 4, NN = 1024, NF = 256, NH = 32;

__device__ __forceinline__ unsigned short f2bf(float x) {
  union { float f; unsigned u; } v; v.f = x;
  unsigned r = v.u + 0x7fffu + ((v.u >> 16) & 1u);
  return (unsigned short)(r >> 16);
}

// ---- Kernel A: wa1 = W@a1, wa2 = W@a2, and W transpose-packed to bf16 ----
// WTp layout: chunk (kc, f) of 8 bf16 holds W[kc*8+s][f], s=0..7  (B-frag = 16B/lane)
__global__ __launch_bounds__(256) void prep_kernel(
    const float* __restrict__ W, const float* __restrict__ a,
    float* __restrict__ wa1, float* __restrict__ wa2,
    unsigned short* __restrict__ WTp) {
  int k = blockIdx.x;     // 0..255 (row of W)
  int t = threadIdx.x;    // 0..255 (col of W)
  float w = W[k * NF + t];
  WTp[(((k >> 3) * NF) + t) * 8 + (k & 7)] = f2bf(w);
  float p1 = w * a[t];
  float p2 = w * a[NF + t];
#pragma unroll
  for (int off = 32; off >= 1; off >>= 1) {
    p1 += __shfl_xor(p1, off);
    p2 += __shfl_xor(p2, off);
  }
  __shared__ float r1[4], r2[4];
  int wid = t >> 6;
  if ((t & 63) == 0) { r1[wid] = p1; r2[wid] = p2; }
  __syncthreads();
  if (t == 0) {
    wa1[k] = r1[0] + r1[1] + r1[2] + r1[3];
    wa2[k] = r2[0] + r2[1] + r2[2] + r2[3];
  }
}

// ---- Kernel B: s1[n] = h[n]·wa1, s2[n] = h[n]·wa2 (full f32) ----
__global__ __launch_bounds__(256) void s_kernel(
    const float* __restrict__ h, const float* __restrict__ wa1,
    const float* __restrict__ wa2, float* __restrict__ s1g,
    float* __restrict__ s2g) {
  int wave = threadIdx.x >> 6, lane = threadIdx.x & 63;
  int n = blockIdx.x * 4 + wave;  // 0..4095
  f32x4 hv = *(const f32x4*)(h + (size_t)n * NF + lane * 4);
  f32x4 av1 = *(const f32x4*)(wa1 + lane * 4);
  f32x4 av2 = *(const f32x4*)(wa2 + lane * 4);
  float d1 = hv.x * av1.x + hv.y * av1.y + hv.z * av1.z + hv.w * av1.w;
  float d2 = hv.x * av2.x + hv.y * av2.y + hv.z * av2.z + hv.w * av2.w;
#pragma unroll
  for (int off = 32; off >= 1; off >>= 1) {
    d1 += __shfl_xor(d1, off);
    d2 += __shfl_xor(d2, off);
  }
  if (lane == 0) { s1g[n] = d1; s2g[n] = d2; }
}

// ---- Kernel C: Wh = h@W in bf16 MFMA, output packed for PV B-frags ----
// WhP layout per batch: chunk (jc, f) of 8 bf16 holds Wh[jc*8+s][f]
__global__ __launch_bounds__(512) void wh_kernel(
    const float* __restrict__ h, const unsigned short* __restrict__ WTp,
    unsigned short* __restrict__ WhP) {
  __shared__ unsigned short hs[16 * 256];  // 8KB, XOR-swizzled
  int bid = blockIdx.x;
  int b = bid >> 6;
  int rb = (bid & 63) << 4;  // 16-row tile base within batch
  int t = threadIdx.x;
  {
    int row = t >> 5, c0 = (t & 31) * 8;
    const float* src = h + (size_t)(b * NN + rb + row) * NF + c0;
    f32x4 v0 = *(const f32x4*)src;
    f32x4 v1 = *(const f32x4*)(src + 4);
    unsigned short tmp[8] = {f2bf(v0.x), f2bf(v0.y), f2bf(v0.z), f2bf(v0.w),
                             f2bf(v1.x), f2bf(v1.y), f2bf(v1.z), f2bf(v1.w)};
    int off = row * 512 + ((c0 * 2) ^ ((row & 7) << 4));
    *(short8*)((char*)hs + off) = *(const short8*)tmp;
  }
  __syncthreads();
  int wid = t >> 6, lane = t & 63;
  int fb = wid * 32;
  int rowa = lane & 15, kg = lane >> 4;
  f32x4 acc0 = {0.f, 0.f, 0.f, 0.f}, acc1 = {0.f, 0.f, 0.f, 0.f};
#pragma unroll
  for (int ks = 0; ks < 8; ++ks) {
    int k0 = ks * 32;
    short8 af = *(const short8*)((const char*)hs + rowa * 512 +
                                 ((2 * (k0 + kg * 8)) ^ ((rowa & 7) << 4)));
    int kc = ks * 4 + kg;
    short8 bf0 = *(const short8*)(WTp + ((kc * NF) + fb + (lane & 15)) * 8);
    short8 bf1 = *(const short8*)(WTp + ((kc * NF) + fb + 16 + (lane & 15)) * 8);
    acc0 = __builtin_amdgcn_mfma_f32_16x16x32_bf16(af, bf0, acc0, 0, 0, 0);
    acc1 = __builtin_amdgcn_mfma_f32_16x16x32_bf16(af, bf1, acc1, 0, 0, 0);
  }
#pragma unroll
  for (int r = 0; r < 4; ++r) {
    int jl = (lane >> 4) * 4 + r;   // local row (C/D layout: row=(lane>>4)*4+reg)
    int j = rb + jl;
    int base = ((b << 7) + (j >> 3)) * NF;
    WhP[(size_t)(base + fb + (lane & 15)) * 8 + (j & 7)] = f2bf(acc0[r]);
    WhP[(size_t)(base + fb + 16 + (lane & 15)) * 8 + (j & 7)] = f2bf(acc1[r]);
  }
}

// ---- Kernel D: fused scores + softmax + PV + ELU ----
__global__ __launch_bounds__(512) void attn_kernel(
    const float* __restrict__ s1g, const float* __restrict__ s2g,
    const float* __restrict__ mz, const int* __restrict__ adj,
    const unsigned short* __restrict__ WhP,
    const float* __restrict__ w1, const float* __restrict__ b1,
    const float* __restrict__ w2, const float* __restrict__ b2,
    float* __restrict__ out) {
  __shared__ unsigned short Pb[16 * 1024];  // 32KB, XOR-swizzled bf16 P
  __shared__ float s2s[1024];
  __shared__ float mzs[1024];
  __shared__ float s1s[16];
  __shared__ float rinv[16];
  int bid = blockIdx.x;
  int b = bid >> 6;
  int rb = (bid & 63) << 4;
  int t = threadIdx.x;
  for (int i = t; i < NN; i += 512) {
    s2s[i] = s2g[b * NN + i];
    mzs[i] = mz[b * NN + i];
  }
  if (t < 16) s1s[t] = s1g[b * NN + rb + t];
  __syncthreads();

  int wid = t >> 6, lane = t & 63;
  float b2v = b2[0];
  for (int rr = 0; rr < 2; ++rr) {
    int row = wid * 2 + rr;   // this wave owns this row entirely
    int ig = rb + row;
    float s1v = s1s[row];
    float mzi = mzs[ig];
    const int* adjrow = adj + ((size_t)b * NN + ig) * NN;
    float e[16];
#pragma unroll
    for (int c = 0; c < 4; ++c) {
      int j0 = c * 256 + lane * 4;
      i32x4 av = *(const i32x4*)(adjrow + j0);
      f32x4 mzv = *(const f32x4*)(mzs + j0);
      f32x4 s2v = *(const f32x4*)(s2s + j0);
      float d[4], acc[4];
#pragma unroll
      for (int u = 0; u < 4; ++u) {
        float dd = fabsf(mzi - mzv[u]);
        d[u] = (ig == 0 || (j0 + u) == 0) ? 0.f : dd;
        acc[u] = b2v;
      }
#pragma unroll
      for (int hh = 0; hh < NH; ++hh) {
        float w1h = w1[hh], b1h = b1[hh], w2h = w2[hh];
#pragma unroll
        for (int u = 0; u < 4; ++u)
          acc[u] += fmaxf(d[u] * w1h + b1h, 0.f) * w2h;
      }
#pragma unroll
      for (int u = 0; u < 4; ++u) {
        float s = s1v + s2v[u];
        s = s > 0.f ? s : ALPHA * s;
        e[c * 4 + u] = (av[u] > 0) ? (s + acc[u]) : NEGINF;
      }
    }
    float m = -3.0e38f;
#pragma unroll
    for (int q = 0; q < 16; ++q) m = fmaxf(m, e[q]);
#pragma unroll
    for (int off = 32; off >= 1; off >>= 1) m = fmaxf(m, __shfl_xor(m, off));
    float sum = 0.f;
#pragma unroll
    for (int q = 0; q < 16; ++q) {
      e[q] = __expf(e[q] - m);
      sum += e[q];
    }
#pragma unroll
    for (int off = 32; off >= 1; off >>= 1) sum += __shfl_xor(sum, off);
#pragma unroll
    for (int c = 0; c < 4; ++c) {
      u16x4 pk = {f2bf(e[c * 4 + 0]), f2bf(e[c * 4 + 1]),
                  f2bf(e[c * 4 + 2]), f2bf(e[c * 4 + 3])};
      int byteoff = row * 2048 + ((512 * c + 8 * lane) ^ ((row & 7) << 4));
      *(u16x4*)((char*)Pb + byteoff) = pk;
    }
    if (lane == 0) rinv[row] = 1.0f / sum;
  }
  __syncthreads();

  // PV: D[i][f] = sum_j P[i][j] * Wh[j][f], per wave: 32 f-cols (2 tiles)
  int fb = wid * 32;
  int rowa = lane & 15, kg = lane >> 4;
  const unsigned short* whb = WhP + (((size_t)b) << 7) * NF * 8;
  f32x4 acc0 = {0.f, 0.f, 0.f, 0.f}, acc1 = {0.f, 0.f, 0.f, 0.f};
#pragma unroll 4
  for (int ks = 0; ks < 32; ++ks) {
    int k0 = ks * 32;
    short8 af = *(const short8*)((const char*)Pb + rowa * 2048 +
                                 ((2 * (k0 + kg * 8)) ^ ((rowa & 7) << 4)));
    int kc = ks * 4 + kg;
    short8 bf0 = *(const short8*)(whb + (size_t)((kc * NF) + fb + (lane & 15)) * 8);
    short8 bf1 = *(const short8*)(whb + (size_t)((kc * NF) + fb + 16 + (lane & 15)) * 8);
    acc0 = __builtin_amdgcn_mfma_f32_16x16x32_bf16(af, bf0, acc0, 0, 0, 0);
    acc1 = __builtin_amdgcn_mfma_f32_16x16x32_bf16(af, bf1, acc1, 0, 0, 0);
  }
#pragma unroll
  for (int r = 0; r < 4; ++r) {
    int il = (lane >> 4) * 4 + r;
    float inv = rinv[il];
    float x0 = acc0[r] * inv;
    float x1 = acc1[r] * inv;
    x0 = x0 > 0.f ? x0 : expm1f(x0);
    x1 = x1 > 0.f ? x1 : expm1f(x1);
    size_t ob = (size_t)(b * NN + rb + il) * NF + fb + (lane & 15);
    out[ob] = x0;
    out[ob + 16] = x1;
  }
}

extern "C" void kernel_launch(void* const* d_in, const int* in_sizes, int n_in,
                              void* d_out, int out_size, void* d_ws, size_t ws_size,
                              hipStream_t stream) {
  const float* h   = (const float*)d_in[0];
  const float* mz  = (const float*)d_in[1];
  const float* W   = (const float*)d_in[2];
  const float* a   = (const float*)d_in[3];
  const float* w1  = (const float*)d_in[4];
  const float* b1  = (const float*)d_in[5];
  const float* w2  = (const float*)d_in[6];
  const float* b2  = (const float*)d_in[7];
  const int*   adj = (const int*)d_in[8];
  float* out = (float*)d_out;

  unsigned short* WTp = (unsigned short*)d_ws;           // 256*256 bf16 = 128KB
  unsigned short* WhP = WTp + 65536;                     // 4*1024*256 bf16 = 2MB
  float* wa1 = (float*)(WhP + (size_t)NB * 128 * NF * 8);
  float* wa2 = wa1 + 256;
  float* s1g = wa2 + 256;
  float* s2g = s1g + NB * NN;

  prep_kernel<<<dim3(256), dim3(256), 0, stream>>>(W, a, wa1, wa2, WTp);
  s_kernel<<<dim3(1024), dim3(256), 0, stream>>>(h, wa1, wa2, s1g, s2g);
  wh_kernel<<<dim3(256), dim3(512), 0, stream>>>(h, WTp, WhP);
  attn_kernel<<<dim3(256), dim3(512), 0, stream>>>(s1g, s2g, mz, adj, WhP,
                                                   w1, b1, w2, b2, out);
}

// Round 2
// 28.946 us; speedup vs baseline: 1.7718x; 1.7718x over previous
//
#include <hip/hip_runtime.h>
#include <hip/hip_bf16.h>

#define ALPHA 0.2f
#define NEGINF -9000000000000000.0f

typedef __attribute__((ext_vector_type(8))) short short8;
typedef __attribute__((ext_vector_type(4))) float f32x4;
typedef __attribute__((ext_vector_type(4))) int i32x4;
typedef __attribute__((ext_vector_type(4))) unsigned short u16x4;

static constexpr int NB = 4, NN = 1024, NF = 256, NH = 32;

__device__ __forceinline__ unsigned short f2bf(float x) {
  union { float f; unsigned u; } v; v.f = x;
  unsigned r = v.u + 0x7fffu + ((v.u >> 16) & 1u);
  return (unsigned short)(r >> 16);
}

// ---- Kernel A: wa1 = W@a1, wa2 = W@a2, W transpose-packed bf16, MLP segment ----
// WTp layout: chunk (kc, f) of 8 bf16 holds W[kc*8+s][f], s=0..7  (B-frag = 16B/lane)
// seg: {singleSegFlag, A, B, 0} such that f(d) = A*d + B for d>=0 when flag!=0
__global__ __launch_bounds__(256) void prep_kernel(
    const float* __restrict__ W, const float* __restrict__ a,
    const float* __restrict__ w1, const float* __restrict__ b1,
    const float* __restrict__ w2, const float* __restrict__ b2,
    float* __restrict__ wa1, float* __restrict__ wa2,
    unsigned short* __restrict__ WTp, float* __restrict__ seg) {
  int k = blockIdx.x;     // 0..255 (row of W)
  int t = threadIdx.x;    // 0..255 (col of W)
  float w = W[k * NF + t];
  WTp[(((k >> 3) * NF) + t) * 8 + (k & 7)] = f2bf(w);
  float p1 = w * a[t];
  float p2 = w * a[NF + t];
#pragma unroll
  for (int off = 32; off >= 1; off >>= 1) {
    p1 += __shfl_xor(p1, off);
    p2 += __shfl_xor(p2, off);
  }
  __shared__ float r1[4], r2[4];
  int wid = t >> 6;
  if ((t & 63) == 0) { r1[wid] = p1; r2[wid] = p2; }
  __syncthreads();
  if (t == 0) {
    wa1[k] = r1[0] + r1[1] + r1[2] + r1[3];
    wa2[k] = r2[0] + r2[1] + r2[2] + r2[3];
  }
  // MLP piecewise-linear analysis (block 0, lanes 0..31 of wave 0)
  if (k == 0 && t < NH) {
    float w1h = w1[t], b1h = b1[t], w2h = w2[t];
    // positive breakpoint exists iff t_h = -b1h/w1h > 0  <=>  signs differ, both nonzero
    bool bp = (w1h != 0.f) && (b1h != 0.f) && ((b1h > 0.f) != (w1h > 0.f));
    // active on (0,inf) single-segment case: sign of w1h*d+b1h constant; test d=1
    bool act = (w1h + b1h) > 0.f;
    float cA = act ? w2h * w1h : 0.f;
    float cB = act ? w2h * b1h : 0.f;
    float nbp = bp ? 1.f : 0.f;
#pragma unroll
    for (int off = 16; off >= 1; off >>= 1) {
      cA += __shfl_xor(cA, off);
      cB += __shfl_xor(cB, off);
      nbp += __shfl_xor(nbp, off);
    }
    if (t == 0) {
      seg[0] = (nbp == 0.f) ? 1.f : 0.f;
      seg[1] = cA;
      seg[2] = cB + b2[0];
      seg[3] = 0.f;
    }
  }
}

// ---- Kernel B: Wh = h@W (bf16 MFMA, packed for PV B-frags) + fused s1/s2 ----
// WhP layout per batch: chunk (jc, f) of 8 bf16 holds Wh[jc*8+s][f]
__global__ __launch_bounds__(512) void wh_kernel(
    const float* __restrict__ h, const unsigned short* __restrict__ WTp,
    const float* __restrict__ wa1, const float* __restrict__ wa2,
    unsigned short* __restrict__ WhP, float* __restrict__ s1g,
    float* __restrict__ s2g) {
  __shared__ unsigned short hs[16 * 256];  // 8KB, XOR-swizzled
  int bid = blockIdx.x;
  int b = bid >> 6;
  int rb = (bid & 63) << 4;  // 16-row tile base within batch
  int t = threadIdx.x;
  {
    int row = t >> 5, c0 = (t & 31) * 8;
    const float* src = h + (size_t)(b * NN + rb + row) * NF + c0;
    f32x4 v0 = *(const f32x4*)src;
    f32x4 v1 = *(const f32x4*)(src + 4);
    unsigned short tmp[8] = {f2bf(v0.x), f2bf(v0.y), f2bf(v0.z), f2bf(v0.w),
                             f2bf(v1.x), f2bf(v1.y), f2bf(v1.z), f2bf(v1.w)};
    int off = row * 512 + ((c0 * 2) ^ ((row & 7) << 4));
    *(short8*)((char*)hs + off) = *(const short8*)tmp;
    // fused s1/s2: f32 h dot wa1/wa2 (exact same math as the old s_kernel)
    f32x4 a10 = *(const f32x4*)(wa1 + c0);
    f32x4 a11 = *(const f32x4*)(wa1 + c0 + 4);
    f32x4 a20 = *(const f32x4*)(wa2 + c0);
    f32x4 a21 = *(const f32x4*)(wa2 + c0 + 4);
    float d1 = v0.x * a10.x + v0.y * a10.y + v0.z * a10.z + v0.w * a10.w +
               v1.x * a11.x + v1.y * a11.y + v1.z * a11.z + v1.w * a11.w;
    float d2 = v0.x * a20.x + v0.y * a20.y + v0.z * a20.z + v0.w * a20.w +
               v1.x * a21.x + v1.y * a21.y + v1.z * a21.z + v1.w * a21.w;
#pragma unroll
    for (int off2 = 16; off2 >= 1; off2 >>= 1) {
      d1 += __shfl_xor(d1, off2);
      d2 += __shfl_xor(d2, off2);
    }
    if ((t & 31) == 0) {
      s1g[b * NN + rb + row] = d1;
      s2g[b * NN + rb + row] = d2;
    }
  }
  __syncthreads();
  int wid = t >> 6, lane = t & 63;
  int fb = wid * 32;
  int rowa = lane & 15, kg = lane >> 4;
  f32x4 acc0 = {0.f, 0.f, 0.f, 0.f}, acc1 = {0.f, 0.f, 0.f, 0.f};
#pragma unroll
  for (int ks = 0; ks < 8; ++ks) {
    int k0 = ks * 32;
    short8 af = *(const short8*)((const char*)hs + rowa * 512 +
                                 ((2 * (k0 + kg * 8)) ^ ((rowa & 7) << 4)));
    int kc = ks * 4 + kg;
    short8 bf0 = *(const short8*)(WTp + ((kc * NF) + fb + (lane & 15)) * 8);
    short8 bf1 = *(const short8*)(WTp + ((kc * NF) + fb + 16 + (lane & 15)) * 8);
    acc0 = __builtin_amdgcn_mfma_f32_16x16x32_bf16(af, bf0, acc0, 0, 0, 0);
    acc1 = __builtin_amdgcn_mfma_f32_16x16x32_bf16(af, bf1, acc1, 0, 0, 0);
  }
#pragma unroll
  for (int r = 0; r < 4; ++r) {
    int jl = (lane >> 4) * 4 + r;   // C/D layout: row=(lane>>4)*4+reg
    int j = rb + jl;
    int base = ((b << 7) + (j >> 3)) * NF;
    WhP[(size_t)(base + fb + (lane & 15)) * 8 + (j & 7)] = f2bf(acc0[r]);
    WhP[(size_t)(base + fb + 16 + (lane & 15)) * 8 + (j & 7)] = f2bf(acc1[r]);
  }
}

// ---- Kernel C: fused scores + softmax + PV + ELU ----
__global__ __launch_bounds__(512) void attn_kernel(
    const float* __restrict__ s1g, const float* __restrict__ s2g,
    const float* __restrict__ mz, const int* __restrict__ adj,
    const unsigned short* __restrict__ WhP,
    const float* __restrict__ w1, const float* __restrict__ b1,
    const float* __restrict__ w2, const float* __restrict__ b2,
    const float* __restrict__ seg, float* __restrict__ out) {
  __shared__ unsigned short Pb[16 * 1024];  // 32KB, XOR-swizzled bf16 P
  __shared__ float s2s[1024];
  __shared__ float mzs[1024];
  __shared__ float s1s[16];
  __shared__ float rinv[16];
  // XCD-aware bijective swizzle (nwg=256, 8 XCDs, 32 blocks/XCD chunk)
  int bid0 = blockIdx.x;
  int bid = (bid0 & 7) * 32 + (bid0 >> 3);
  int b = bid >> 6;
  int rb = (bid & 63) << 4;
  int t = threadIdx.x;
  for (int i = t; i < NN; i += 512) {
    s2s[i] = s2g[b * NN + i];
    mzs[i] = mz[b * NN + i];
  }
  if (t < 16) s1s[t] = s1g[b * NN + rb + t];
  __syncthreads();

  int wid = t >> 6, lane = t & 63;
  float segF = seg[0], segA = seg[1], segB = seg[2];
  float b2v = b2[0];
  for (int rr = 0; rr < 2; ++rr) {
    int row = wid * 2 + rr;   // this wave owns this row entirely
    int ig = rb + row;
    float s1v = s1s[row];
    float mzi = mzs[ig];
    const int* adjrow = adj + ((size_t)b * NN + ig) * NN;
    float e[16];
    if (segF != 0.f) {
      // fast path: MLP == segA*d + segB exactly on d>=0
#pragma unroll
      for (int c = 0; c < 4; ++c) {
        int j0 = c * 256 + lane * 4;
        i32x4 av = *(const i32x4*)(adjrow + j0);
        f32x4 mzv = *(const f32x4*)(mzs + j0);
        f32x4 s2v = *(const f32x4*)(s2s + j0);
#pragma unroll
        for (int u = 0; u < 4; ++u) {
          float dd = fabsf(mzi - mzv[u]);
          float d = (ig == 0 || (j0 + u) == 0) ? 0.f : dd;
          float s = s1v + s2v[u];
          s = fmaxf(s, 0.f) + ALPHA * fminf(s, 0.f);
          float ee = s + fmaf(d, segA, segB);
          e[c * 4 + u] = (av[u] > 0) ? ee : NEGINF;
        }
      }
    } else {
      // general fallback: full 32-hidden MLP
#pragma unroll
      for (int c = 0; c < 4; ++c) {
        int j0 = c * 256 + lane * 4;
        i32x4 av = *(const i32x4*)(adjrow + j0);
        f32x4 mzv = *(const f32x4*)(mzs + j0);
        f32x4 s2v = *(const f32x4*)(s2s + j0);
        float d[4], acc[4];
#pragma unroll
        for (int u = 0; u < 4; ++u) {
          float dd = fabsf(mzi - mzv[u]);
          d[u] = (ig == 0 || (j0 + u) == 0) ? 0.f : dd;
          acc[u] = b2v;
        }
#pragma unroll
        for (int hh = 0; hh < NH; ++hh) {
          float w1h = w1[hh], b1h = b1[hh], w2h = w2[hh];
#pragma unroll
          for (int u = 0; u < 4; ++u)
            acc[u] += fmaxf(d[u] * w1h + b1h, 0.f) * w2h;
        }
#pragma unroll
        for (int u = 0; u < 4; ++u) {
          float s = s1v + s2v[u];
          s = s > 0.f ? s : ALPHA * s;
          e[c * 4 + u] = (av[u] > 0) ? (s + acc[u]) : NEGINF;
        }
      }
    }
    float m = -3.0e38f;
#pragma unroll
    for (int q = 0; q < 16; ++q) m = fmaxf(m, e[q]);
#pragma unroll
    for (int off = 32; off >= 1; off >>= 1) m = fmaxf(m, __shfl_xor(m, off));
    float sum = 0.f;
#pragma unroll
    for (int q = 0; q < 16; ++q) {
      e[q] = __expf(e[q] - m);
      sum += e[q];
    }
#pragma unroll
    for (int off = 32; off >= 1; off >>= 1) sum += __shfl_xor(sum, off);
#pragma unroll
    for (int c = 0; c < 4; ++c) {
      u16x4 pk = {f2bf(e[c * 4 + 0]), f2bf(e[c * 4 + 1]),
                  f2bf(e[c * 4 + 2]), f2bf(e[c * 4 + 3])};
      int byteoff = row * 2048 + ((512 * c + 8 * lane) ^ ((row & 7) << 4));
      *(u16x4*)((char*)Pb + byteoff) = pk;
    }
    if (lane == 0) rinv[row] = 1.0f / sum;
  }
  __syncthreads();

  // PV: D[i][f] = sum_j P[i][j] * Wh[j][f], per wave: 32 f-cols (2 tiles)
  int fb = wid * 32;
  int rowa = lane & 15, kg = lane >> 4;
  const unsigned short* whb = WhP + (((size_t)b) << 7) * NF * 8;
  f32x4 acc0 = {0.f, 0.f, 0.f, 0.f}, acc1 = {0.f, 0.f, 0.f, 0.f};
#pragma unroll 4
  for (int ks = 0; ks < 32; ++ks) {
    int k0 = ks * 32;
    short8 af = *(const short8*)((const char*)Pb + rowa * 2048 +
                                 ((2 * (k0 + kg * 8)) ^ ((rowa & 7) << 4)));
    int kc = ks * 4 + kg;
    short8 bf0 = *(const short8*)(whb + (size_t)((kc * NF) + fb + (lane & 15)) * 8);
    short8 bf1 = *(const short8*)(whb + (size_t)((kc * NF) + fb + 16 + (lane & 15)) * 8);
    acc0 = __builtin_amdgcn_mfma_f32_16x16x32_bf16(af, bf0, acc0, 0, 0, 0);
    acc1 = __builtin_amdgcn_mfma_f32_16x16x32_bf16(af, bf1, acc1, 0, 0, 0);
  }
#pragma unroll
  for (int r = 0; r < 4; ++r) {
    int il = (lane >> 4) * 4 + r;
    float inv = rinv[il];
    float x0 = acc0[r] * inv;
    float x1 = acc1[r] * inv;
    x0 = x0 > 0.f ? x0 : expm1f(x0);
    x1 = x1 > 0.f ? x1 : expm1f(x1);
    size_t ob = (size_t)(b * NN + rb + il) * NF + fb + (lane & 15);
    out[ob] = x0;
    out[ob + 16] = x1;
  }
}

extern "C" void kernel_launch(void* const* d_in, const int* in_sizes, int n_in,
                              void* d_out, int out_size, void* d_ws, size_t ws_size,
                              hipStream_t stream) {
  const float* h   = (const float*)d_in[0];
  const float* mz  = (const float*)d_in[1];
  const float* W   = (const float*)d_in[2];
  const float* a   = (const float*)d_in[3];
  const float* w1  = (const float*)d_in[4];
  const float* b1  = (const float*)d_in[5];
  const float* w2  = (const float*)d_in[6];
  const float* b2  = (const float*)d_in[7];
  const int*   adj = (const int*)d_in[8];
  float* out = (float*)d_out;

  unsigned short* WTp = (unsigned short*)d_ws;           // 256*256 bf16 = 128KB
  unsigned short* WhP = WTp + 65536;                     // 4*1024*256 bf16 = 2MB
  float* wa1 = (float*)(WhP + (size_t)NB * 128 * NF * 8);
  float* wa2 = wa1 + 256;
  float* s1g = wa2 + 256;
  float* s2g = s1g + NB * NN;
  float* segb = s2g + NB * NN;

  prep_kernel<<<dim3(256), dim3(256), 0, stream>>>(W, a, w1, b1, w2, b2,
                                                   wa1, wa2, WTp, segb);
  wh_kernel<<<dim3(256), dim3(512), 0, stream>>>(h, WTp, wa1, wa2, WhP, s1g, s2g);
  attn_kernel<<<dim3(256), dim3(512), 0, stream>>>(s1g, s2g, mz, adj, WhP,
                                                   w1, b1, w2, b2, segb, out);
}